// Round 1
// baseline (132.660 us; speedup 1.0000x reference)
//
#include <hip/hip_runtime.h>

// Grouped masked GEMM (DeepSeekMOE up/gate + down), fp32 in/out, bf16 MFMA compute.
// G=8, M=32. up/gate: K=4096,N=2816. down: K=1408,N=4096. out: [G,32,5632] f32.

#define G_    8
#define M_    32
#define KUG   4096
#define NUG   2816
#define KDN   1408
#define NDN   4096
#define NOUT  (NUG + NDN)          // 5632
#define BN    64
#define BK    64
#define NBUP  (G_ * (NUG / BN))    // 8*44 = 352
#define NBDN  (G_ * (NDN / BN))    // 8*64 = 512

typedef __attribute__((ext_vector_type(8))) short  bf16x8;
typedef __attribute__((ext_vector_type(4))) float  f32x4;

typedef __attribute__((address_space(3))) float        lds_f32;
typedef const __attribute__((address_space(1))) float  gbl_f32;

// fp32 -> bf16 round-to-nearest-even (bit trick; inputs are finite gaussians)
__device__ __forceinline__ short f2bf(float x) {
  unsigned u = __float_as_uint(x);
  u = u + 0x7fffu + ((u >> 16) & 1u);
  return (short)(u >> 16);
}

// read 8 contiguous f32 from LDS, convert to bf16x8 fragment
__device__ __forceinline__ bf16x8 cvt_frag(const float* p) {
  f32x4 lo = *(const f32x4*)p;
  f32x4 hi = *(const f32x4*)(p + 4);
  bf16x8 o;
#pragma unroll
  for (int j = 0; j < 4; ++j) { o[j] = f2bf(lo[j]); o[4 + j] = f2bf(hi[j]); }
  return o;
}

// Stage one BK-tile: W[64 rows][64 k] + X[32 rows][64 k], fp32, linear LDS layout.
// 256 threads; global_load_lds width 16 (4 f32 per lane per call).
__device__ __forceinline__ void stage(float* dst, const float* wg, const float* xg,
                                      int K, int k0, int t) {
#pragma unroll
  for (int rr = 0; rr < 4; ++rr) {            // W tile: 1024 granules of 16B
    int gr  = rr * 256 + t;
    int row = gr >> 4;
    int col = (gr & 15) << 2;
    __builtin_amdgcn_global_load_lds((gbl_f32*)(wg + (size_t)row * K + k0 + col),
                                     (lds_f32*)(dst + gr * 4), 16, 0, 0);
  }
#pragma unroll
  for (int rr = 0; rr < 2; ++rr) {            // X tile: 512 granules
    int gr  = rr * 256 + t;
    int row = gr >> 4;
    int col = (gr & 15) << 2;
    __builtin_amdgcn_global_load_lds((gbl_f32*)(xg + (size_t)row * K + k0 + col),
                                     (lds_f32*)(dst + 4096 + gr * 4), 16, 0, 0);
  }
}

__global__ __launch_bounds__(256, 3) void moe_masked_gemm(
    const float* __restrict__ x_ug, const float* __restrict__ w_ug,
    const float* __restrict__ x_dn, const float* __restrict__ w_dn,
    const int* __restrict__ masked_m, float* __restrict__ out) {
  __shared__ float lds[2][64 * 64 + 32 * 64];  // W tile + X tile, double buffered (48 KB)

  int b = blockIdx.x;
  const float* xg;
  const float* wg;
  int K, NIT, g, nb, colOff;
  if (b < NBUP) {
    g = b / 44; nb = b - g * 44;
    K = KUG; NIT = KUG / BK; colOff = 0;
    wg = w_ug + ((size_t)g * NUG + (size_t)nb * BN) * KUG;
    xg = x_ug + (size_t)g * M_ * KUG;
  } else {
    int b2 = b - NBUP;
    g = b2 >> 6; nb = b2 & 63;
    K = KDN; NIT = KDN / BK; colOff = NUG;
    wg = w_dn + ((size_t)g * NDN + (size_t)nb * BN) * KDN;
    xg = x_dn + (size_t)g * M_ * KDN;
  }

  int t  = threadIdx.x;
  int mm = masked_m[g];
  float* outg = out + (size_t)g * M_ * NOUT + colOff + (size_t)nb * BN;

  if (mm == 0) {                    // whole group's rows are masked: write zeros, skip all reads
#pragma unroll
    for (int i = 0; i < 8; ++i) {
      int e = i * 256 + t;
      outg[(size_t)(e >> 6) * NOUT + (e & 63)] = 0.f;
    }
    return;
  }

  int lane = t & 63, wv = t >> 6;   // wave 0..3 owns n-cols [wv*16, wv*16+16)
  int r = lane & 15, kb = lane >> 4;

  f32x4 acc0 = {0.f, 0.f, 0.f, 0.f};
  f32x4 acc1 = {0.f, 0.f, 0.f, 0.f};

  stage(&lds[0][0], wg, xg, K, 0, t);
  __syncthreads();

  int cur = 0;
  for (int it = 0; it < NIT; ++it) {
    if (it + 1 < NIT) stage(&lds[cur ^ 1][0], wg, xg, K, (it + 1) * BK, t);

    const float* Ws = &lds[cur][0];       // [64][64] f32
    const float* Xs = Ws + 64 * 64;       // [32][64] f32
#pragma unroll
    for (int kc = 0; kc < 2; ++kc) {
      int ko = kc * 32 + kb * 8;          // lane's 8 contiguous k
      bf16x8 a0 = cvt_frag(Xs + r * 64 + ko);
      bf16x8 a1 = cvt_frag(Xs + (r + 16) * 64 + ko);
      bf16x8 bb = cvt_frag(Ws + (wv * 16 + r) * 64 + ko);
      acc0 = __builtin_amdgcn_mfma_f32_16x16x32_bf16(a0, bb, acc0, 0, 0, 0);
      acc1 = __builtin_amdgcn_mfma_f32_16x16x32_bf16(a1, bb, acc1, 0, 0, 0);
    }
    __syncthreads();                      // drains our gload_lds (vmcnt) + ds_reads (lgkm)
    cur ^= 1;
  }

  // Epilogue: C/D layout col=lane&15, row=(lane>>4)*4+i (m89-verified). Mask rows >= mm.
  float* op = outg + wv * 16 + r;
  int m0 = kb * 4;
#pragma unroll
  for (int i = 0; i < 4; ++i) {
    op[(size_t)(m0 + i) * NOUT]      = (m0 + i      < mm) ? acc0[i] : 0.f;
    op[(size_t)(m0 + i + 16) * NOUT] = (m0 + i + 16 < mm) ? acc1[i] : 0.f;
  }
}

extern "C" void kernel_launch(void* const* d_in, const int* in_sizes, int n_in,
                              void* d_out, int out_size, void* d_ws, size_t ws_size,
                              hipStream_t stream) {
  const float* x_ug     = (const float*)d_in[0];
  const float* w_ug     = (const float*)d_in[1];
  const float* x_dn     = (const float*)d_in[2];
  const float* w_dn     = (const float*)d_in[3];
  const int*   masked_m = (const int*)d_in[4];
  float*       out      = (float*)d_out;

  moe_masked_gemm<<<dim3(NBUP + NBDN), dim3(256), 0, stream>>>(
      x_ug, w_ug, x_dn, w_dn, masked_m, out);
}